// Round 4
// baseline (125.336 us; speedup 1.0000x reference)
//
#include <hip/hip_runtime.h>

#define Bn 16
#define Ln 128
#define Hn 256
#define Dn 256

// Output layout (flat fp32 concat, reference return order)
#define OFF_MASK   0          // (B,L,L) 262144
#define OFF_SMP    262144     // (B,L,L) 262144
#define OFF_ENT    524288     // (B,L,L) 262144
#define OFF_GRAPH  786432     // (L,L)   16384
#define OFF_LSE    802816     // scalar
#define OFF_EREG   802817     // (B,)    16

static __device__ __forceinline__ unsigned rotl32(unsigned x, int r) {
  return (x << r) | (x >> (32 - r));
}

// Threefry-2x32, 20 rounds, key = (0,1)  [jax.random.key(1)], partitionable
// random-bits path: counter = (hi=0, lo=flat_index), output = y0 ^ y1.
static __device__ __forceinline__ unsigned threefry_bits(unsigned c_hi, unsigned c_lo) {
  const unsigned ks0 = 0u, ks1 = 1u;
  const unsigned ks2 = 0u ^ 1u ^ 0x1BD11BDAu;
  unsigned x0 = c_hi + ks0;
  unsigned x1 = c_lo + ks1;
  x0 += x1; x1 = rotl32(x1, 13); x1 ^= x0;
  x0 += x1; x1 = rotl32(x1, 15); x1 ^= x0;
  x0 += x1; x1 = rotl32(x1, 26); x1 ^= x0;
  x0 += x1; x1 = rotl32(x1, 6);  x1 ^= x0;
  x0 += ks1; x1 += ks2 + 1u;
  x0 += x1; x1 = rotl32(x1, 17); x1 ^= x0;
  x0 += x1; x1 = rotl32(x1, 29); x1 ^= x0;
  x0 += x1; x1 = rotl32(x1, 16); x1 ^= x0;
  x0 += x1; x1 = rotl32(x1, 24); x1 ^= x0;
  x0 += ks2; x1 += ks0 + 2u;
  x0 += x1; x1 = rotl32(x1, 13); x1 ^= x0;
  x0 += x1; x1 = rotl32(x1, 15); x1 ^= x0;
  x0 += x1; x1 = rotl32(x1, 26); x1 ^= x0;
  x0 += x1; x1 = rotl32(x1, 6);  x1 ^= x0;
  x0 += ks0; x1 += ks1 + 3u;
  x0 += x1; x1 = rotl32(x1, 17); x1 ^= x0;
  x0 += x1; x1 = rotl32(x1, 29); x1 ^= x0;
  x0 += x1; x1 = rotl32(x1, 16); x1 ^= x0;
  x0 += x1; x1 = rotl32(x1, 24); x1 ^= x0;
  x0 += ks1; x1 += ks2 + 4u;
  x0 += x1; x1 = rotl32(x1, 13); x1 ^= x0;
  x0 += x1; x1 = rotl32(x1, 15); x1 ^= x0;
  x0 += x1; x1 = rotl32(x1, 26); x1 ^= x0;
  x0 += x1; x1 = rotl32(x1, 6);  x1 ^= x0;
  x0 += ks2; x1 += ks0 + 5u;
  return x0 ^ x1;
}

static __device__ __forceinline__ float softplus_f(float x) {
  // max(x,0) + log1p(exp(-|x|)); exact at |x|=1e8 (exp(-1e8)=0)
  return fmaxf(x, 0.0f) + log1pf(__expf(-fabsf(x)));
}

static __device__ __forceinline__ float fast_tanh(float x) {
  // tanh(x) = 2/(1+e^{-2x}) - 1; saturates correctly for |x| large
  float e = __expf(-2.0f * x);
  float r = __builtin_amdgcn_rcpf(1.0f + e);
  return fmaf(2.0f, r, -1.0f);
}

// proj v4: 1024 blocks (4/CU, 16 waves/CU — was 512 = 2/CU latency-starved).
// Block = 16 rows x 64 d-cols x ONE matrix: W traffic 64KB/block -> 64MB L2
// total (was 256MB). enc tile (16KB) staged once; W streamed direct from
// L2 with unroll-8 load batching; NO barrier in the K-loop (R3's per-chunk
// vmcnt(0) drain serialized DMA vs compute). Each output is the SAME
// h-ascending fmaf(e, w, acc) chain as R0/R3 -> dl/dr bit-identical.
__global__ void proj_kernel(const float* __restrict__ enc,
                            const float* __restrict__ Wl,
                            const float* __restrict__ Wr,
                            float* __restrict__ dl,
                            float* __restrict__ dr,
                            float* __restrict__ out,
                            double* __restrict__ ws_acc) {
  int gid = blockIdx.x * blockDim.x + threadIdx.x;
  if (gid < Ln * Ln) out[OFF_GRAPH + gid] = 0.0f;
  if (gid < 18) ws_acc[gid] = 0.0;

  int g = blockIdx.x;            // rg(7b) | mat(1b) | dq(2b)
  int rg = g >> 3;               // 0..127 -> 16-row group
  int mat = (g >> 2) & 1;        // 0 -> Wl/dl, 1 -> Wr/dr
  int dq = g & 3;                // 0..3 -> 64-col group
  int r0 = rg * 16;
  int d0 = dq * 64;

  int t = threadIdx.x;
  int dcol = d0 + (t & 63);      // wave lanes -> consecutive d: coalesced
  int rsub = t >> 6;             // wave id -> 4-row subgroup

  __shared__ float encS[16][Hn];   // 16 KB
#pragma unroll
  for (int q = 0; q < 4; ++q)
    ((float4*)encS)[q * 256 + t] = ((const float4*)(enc + (size_t)r0 * Hn))[q * 256 + t];
  __syncthreads();

  const float* wp = (mat ? Wr : Wl) + dcol;   // column dcol, stride Dn
  float a[4] = {0.f, 0.f, 0.f, 0.f};

  for (int h8 = 0; h8 < Hn / 8; ++h8) {
    float wv[8];
#pragma unroll
    for (int u = 0; u < 8; ++u) wv[u] = wp[(size_t)(h8 * 8 + u) * Dn];
#pragma unroll
    for (int u = 0; u < 8; ++u) {
      int h = h8 * 8 + u;        // h ascending overall -> same chain order
#pragma unroll
      for (int rr = 0; rr < 4; ++rr)
        a[rr] = fmaf(encS[rsub * 4 + rr][h], wv[u], a[rr]);
    }
  }

  float* dst = mat ? dr : dl;
#pragma unroll
  for (int rr = 0; rr < 4; ++rr)
    dst[(size_t)(r0 + rsub * 4 + rr) * Dn + dcol] = a[rr];
}

// Grid 1024 = (b:16, iq:32, jseg:2); block = 4 i-rows x 64 j x 256 d.
// EXACT R3 form (unchanged this round; near transcendental-pipe roofline:
// VALUBusy 35% ~= the 38% issue ceiling implied by exp+rcp quarter-rate).
// Chunk-sum dp-ascending -> outputs bit-identical. Fused last-block finalize.
__global__ void pair_kernel(const float* __restrict__ dl,
                            const float* __restrict__ dr,
                            const float* __restrict__ U,
                            const float* __restrict__ bias,
                            float* __restrict__ out,
                            double* __restrict__ ws_acc) {
  int blk = blockIdx.x;          // b*64 + iq*2 + jseg
  int b = blk >> 6;              // 0..15
  int i0 = ((blk >> 1) & 31) * 4;
  int j0 = (blk & 1) * 64;
  int t = threadIdx.x;
  int dp = t & 15;
  int jj = t >> 4;

  __shared__ float dlS[4][Dn];        // 4 KB, cooperative coalesced stage
  __shared__ float pS[4][64 * 17];    // [row][jl*17 + dp], padded, 17 KB
  __shared__ float redS[8];

  // stage dl rows i0..i0+3 with one coalesced float4 load per thread
  ((float4*)dlS)[t] = ((const float4*)(dl + (size_t)(b * Ln + i0) * Dn))[t];

  float Ur[16];
  {
    const float4* U4 = (const float4*)(U + dp * 16);
#pragma unroll
    for (int q = 0; q < 4; ++q) {
      float4 u = U4[q];
      Ur[4*q+0] = u.x; Ur[4*q+1] = u.y; Ur[4*q+2] = u.z; Ur[4*q+3] = u.w;
    }
  }
  __syncthreads();

  float dlr[4][16];
#pragma unroll
  for (int r = 0; r < 4; ++r) {
#pragma unroll
    for (int q = 0; q < 4; ++q) {
      float4 a = *(const float4*)&dlS[r][dp * 16 + q * 4];
      dlr[r][4*q+0] = a.x; dlr[r][4*q+1] = a.y; dlr[r][4*q+2] = a.z; dlr[r][4*q+3] = a.w;
    }
  }

  const float* drt = dr + (size_t)b * Ln * Dn + (size_t)(j0 + jj) * Dn + dp * 16;
#pragma unroll
  for (int tl = 0; tl < 4; ++tl) {
    const float4* drp = (const float4*)(drt + (size_t)tl * 16 * Dn);
    float a0 = 0.f, a1 = 0.f, a2 = 0.f, a3 = 0.f;
#pragma unroll
    for (int q = 0; q < 4; ++q) {
      float4 v = drp[q];
#pragma unroll
      for (int c = 0; c < 4; ++c) {
        float dv = (c == 0) ? v.x : (c == 1) ? v.y : (c == 2) ? v.z : v.w;
        float uv = Ur[4*q+c];
        a0 = fmaf(fast_tanh(dlr[0][4*q+c] + dv), uv, a0);
        a1 = fmaf(fast_tanh(dlr[1][4*q+c] + dv), uv, a1);
        a2 = fmaf(fast_tanh(dlr[2][4*q+c] + dv), uv, a2);
        a3 = fmaf(fast_tanh(dlr[3][4*q+c] + dv), uv, a3);
      }
    }
    int sa = (tl * 16 + jj) * 17 + dp;   // jl*17 + dp, jl = tl*16+jj
    pS[0][sa] = a0; pS[1][sa] = a1; pS[2][sa] = a2; pS[3][sa] = a3;
  }
  __syncthreads();

  // epilogue: 256 outputs (4 rows x 64 j); thread t -> row = t>>6, jl = t&63
  int row = t >> 6;
  int jl = t & 63;
  int j = j0 + jl;
  const float* ps = &pS[row][jl * 17];
  float tot = 0.0f;
#pragma unroll
  for (int k = 0; k < 16; ++k) tot += ps[k];   // dp-ascending, same as R9
  int i = i0 + row;
  float l = tot + bias[0] - ((j == i) ? 1.0e8f : 0.0f);
  float e = __expf(-l);                       // l=-1e8 -> inf
  float p = __builtin_amdgcn_rcpf(1.0f + e);  // -> 0 on diagonal
  unsigned n = ((unsigned)(b * Ln + i) << 7) | (unsigned)j;
  unsigned bits = threefry_bits(0u, n);
  float u = __uint_as_float((bits >> 9) | 0x3f800000u) - 1.0f;
  float smp = (u < p) ? 1.0f : 0.0f;
  float sp_pos = softplus_f(l);
  float sp_neg = softplus_f(-l);
  float ent = p * sp_neg + (1.0f - p) * sp_pos;
  size_t idx = (size_t)(b * Ln + i) * Ln + j;
  out[OFF_MASK + idx] = l;
  out[OFF_SMP + idx] = smp;
  out[OFF_ENT + idx] = ent;
  atomicAdd(&out[OFF_GRAPH + i * Ln + j], smp * 0.0625f);
  float ent_v = ent;
  float lse_v = sp_pos - l * smp;

  // reduce over the 4 waves (all lanes valid)
#pragma unroll
  for (int off = 32; off > 0; off >>= 1) {
    ent_v += __shfl_down(ent_v, off);
    lse_v += __shfl_down(lse_v, off);
  }
  if ((t & 63) == 0) {
    redS[(t >> 6) * 2 + 0] = ent_v;
    redS[(t >> 6) * 2 + 1] = lse_v;
  }
  __syncthreads();
  if (t == 0) {
    float es = redS[0] + redS[2] + redS[4] + redS[6];
    float ls = redS[1] + redS[3] + redS[5] + redS[7];
    atomicAdd(&ws_acc[b], (double)es);
    atomicAdd(&ws_acc[16], (double)ls);
    __threadfence();   // make this block's ws atomics visible before counter
    unsigned int* ctr = (unsigned int*)&ws_acc[17];
    unsigned done = atomicAdd(ctr, 1u);
    if (done == (unsigned)(gridDim.x - 1)) {
      // fused finalize: all blocks' device-scope atomics are complete.
      // atomicAdd(,0.0) = L2-coherent read (bypasses potentially stale L1).
      double ls_tot = atomicAdd(&ws_acc[16], 0.0);
      out[OFF_LSE] = (float)(ls_tot / (double)(Bn * Ln * Ln));
      for (int q = 0; q < Bn; ++q) {
        double ev = atomicAdd(&ws_acc[q], 0.0);
        out[OFF_EREG + q] = (float)(ev / (double)(Ln * Ln));
      }
    }
  }
}

extern "C" void kernel_launch(void* const* d_in, const int* in_sizes, int n_in,
                              void* d_out, int out_size, void* d_ws, size_t ws_size,
                              hipStream_t stream) {
  const float* enc = (const float*)d_in[0];
  const float* Wl = (const float*)d_in[1];
  const float* Wr = (const float*)d_in[2];
  const float* U = (const float*)d_in[3];
  const float* bias = (const float*)d_in[4];
  float* out = (float*)d_out;

  // ws layout: dl (2048*256 f32), dr (2048*256 f32), 17 dbl acc + counter
  float* dl = (float*)d_ws;
  float* dr = dl + (size_t)Bn * Ln * Dn;
  double* ws_acc = (double*)(dr + (size_t)Bn * Ln * Dn);

  proj_kernel<<<1024, 256, 0, stream>>>(enc, Wl, Wr, dl, dr, out, ws_acc);
  pair_kernel<<<Bn * Ln / 2, 256, 0, stream>>>(dl, dr, U, bias, out, ws_acc);
}

// Round 5
// 124.153 us; speedup vs baseline: 1.0095x; 1.0095x over previous
//
#include <hip/hip_runtime.h>

#define Bn 16
#define Ln 128
#define Hn 256
#define Dn 256

// Output layout (flat fp32 concat, reference return order)
#define OFF_MASK   0          // (B,L,L) 262144
#define OFF_SMP    262144     // (B,L,L) 262144
#define OFF_ENT    524288     // (B,L,L) 262144
#define OFF_GRAPH  786432     // (L,L)   16384
#define OFF_LSE    802816     // scalar
#define OFF_EREG   802817     // (B,)    16

static __device__ __forceinline__ unsigned rotl32(unsigned x, int r) {
  return (x << r) | (x >> (32 - r));
}

// Threefry-2x32, 20 rounds, key = (0,1)  [jax.random.key(1)], partitionable
// random-bits path: counter = (hi=0, lo=flat_index), output = y0 ^ y1.
static __device__ __forceinline__ unsigned threefry_bits(unsigned c_hi, unsigned c_lo) {
  const unsigned ks0 = 0u, ks1 = 1u;
  const unsigned ks2 = 0u ^ 1u ^ 0x1BD11BDAu;
  unsigned x0 = c_hi + ks0;
  unsigned x1 = c_lo + ks1;
  x0 += x1; x1 = rotl32(x1, 13); x1 ^= x0;
  x0 += x1; x1 = rotl32(x1, 15); x1 ^= x0;
  x0 += x1; x1 = rotl32(x1, 26); x1 ^= x0;
  x0 += x1; x1 = rotl32(x1, 6);  x1 ^= x0;
  x0 += ks1; x1 += ks2 + 1u;
  x0 += x1; x1 = rotl32(x1, 17); x1 ^= x0;
  x0 += x1; x1 = rotl32(x1, 29); x1 ^= x0;
  x0 += x1; x1 = rotl32(x1, 16); x1 ^= x0;
  x0 += x1; x1 = rotl32(x1, 24); x1 ^= x0;
  x0 += ks2; x1 += ks0 + 2u;
  x0 += x1; x1 = rotl32(x1, 13); x1 ^= x0;
  x0 += x1; x1 = rotl32(x1, 15); x1 ^= x0;
  x0 += x1; x1 = rotl32(x1, 26); x1 ^= x0;
  x0 += x1; x1 = rotl32(x1, 6);  x1 ^= x0;
  x0 += ks0; x1 += ks1 + 3u;
  x0 += x1; x1 = rotl32(x1, 17); x1 ^= x0;
  x0 += x1; x1 = rotl32(x1, 29); x1 ^= x0;
  x0 += x1; x1 = rotl32(x1, 16); x1 ^= x0;
  x0 += x1; x1 = rotl32(x1, 24); x1 ^= x0;
  x0 += ks1; x1 += ks2 + 4u;
  x0 += x1; x1 = rotl32(x1, 13); x1 ^= x0;
  x0 += x1; x1 = rotl32(x1, 15); x1 ^= x0;
  x0 += x1; x1 = rotl32(x1, 26); x1 ^= x0;
  x0 += x1; x1 = rotl32(x1, 6);  x1 ^= x0;
  x0 += ks2; x1 += ks0 + 5u;
  return x0 ^ x1;
}

static __device__ __forceinline__ float softplus_f(float x) {
  // max(x,0) + log1p(exp(-|x|)); exact at |x|=1e8 (exp(-1e8)=0)
  return fmaxf(x, 0.0f) + log1pf(__expf(-fabsf(x)));
}

static __device__ __forceinline__ float fast_tanh(float x) {
  // tanh(x) = 2/(1+e^{-2x}) - 1; saturates correctly for |x| large
  float e = __expf(-2.0f * x);
  float r = __builtin_amdgcn_rcpf(1.0f + e);
  return fmaf(2.0f, r, -1.0f);
}

// proj v5: 512 blocks = (rg:256 x mat:2); block = 8 rows x 256 d-cols.
// Thread owns 4 consecutive d (float4 W loads: 16B/lane, 4x fewer VMEM
// instrs than v4's scalar stream) and 2 rows. enc is read via wave-uniform
// SCALAR loads (readfirstlane row -> SGPR base -> s_load on the free scalar
// pipe): kills v4's 1024 ds_read_b32/thread AND the encS stage + barrier.
// v4 was issue-bound on LDS/VMEM scalar ops (45us vs 3.4us VALU floor).
// Per-output chain unchanged: acc = fmaf(e[h], w[h], acc), h ascending ->
// dl/dr bit-identical.
__global__ __launch_bounds__(256) void proj_kernel(
                            const float* __restrict__ enc,
                            const float* __restrict__ Wl,
                            const float* __restrict__ Wr,
                            float* __restrict__ dl,
                            float* __restrict__ dr,
                            float* __restrict__ out,
                            double* __restrict__ ws_acc) {
  int gid = blockIdx.x * blockDim.x + threadIdx.x;
  if (gid < Ln * Ln) out[OFF_GRAPH + gid] = 0.0f;
  if (gid < 18) ws_acc[gid] = 0.0;

  int g = blockIdx.x;            // 512 blocks
  int rg = g >> 1;               // 0..255 -> 8-row group
  int mat = g & 1;               // 0 -> Wl/dl, 1 -> Wr/dr
  int r0 = rg * 8;

  int t = threadIdx.x;
  int d4 = (t & 63) * 4;         // 4 consecutive d-cols; lanes -> 1KB coalesced
  int rsub = t >> 6;             // wave id -> row pair

  // wave-uniform row index -> SGPR -> scalar loads of enc
  int row0 = __builtin_amdgcn_readfirstlane(r0 + rsub * 2);
  const float* ep0 = enc + (size_t)row0 * Hn;
  const float* ep1 = ep0 + Hn;
  const float* wbase = (mat ? Wr : Wl) + d4;

  float4 a0 = {0.f, 0.f, 0.f, 0.f};
  float4 a1 = {0.f, 0.f, 0.f, 0.f};

#pragma unroll 2
  for (int h8 = 0; h8 < Hn / 8; ++h8) {
    float4 w[8];
#pragma unroll
    for (int u = 0; u < 8; ++u)
      w[u] = *(const float4*)(wbase + (size_t)(h8 * 8 + u) * Dn);
#pragma unroll
    for (int u = 0; u < 8; ++u) {
      int h = h8 * 8 + u;        // h ascending overall -> same chain order
      float e0 = ep0[h];
      float e1 = ep1[h];
      a0.x = fmaf(e0, w[u].x, a0.x);
      a0.y = fmaf(e0, w[u].y, a0.y);
      a0.z = fmaf(e0, w[u].z, a0.z);
      a0.w = fmaf(e0, w[u].w, a0.w);
      a1.x = fmaf(e1, w[u].x, a1.x);
      a1.y = fmaf(e1, w[u].y, a1.y);
      a1.z = fmaf(e1, w[u].z, a1.z);
      a1.w = fmaf(e1, w[u].w, a1.w);
    }
  }

  float* dst = (mat ? dr : dl) + (size_t)(r0 + rsub * 2) * Dn + d4;
  *(float4*)dst = a0;
  *(float4*)(dst + Dn) = a1;
}

// Grid 1024 = (b:16, iq:32, jseg:2); block = 4 i-rows x 64 j x 256 d.
// R3 structure + two changes: __launch_bounds__(256,4) raises the VGPR cap
// 60->128 at the SAME 4 blocks/CU (16 waves/CU), and the dr float4 loads are
// explicitly prefetched one tl ahead into a statically-unrolled register
// double buffer -- at VGPR=60 the compiler couldn't hoist them, so each tl
// ate raw L2 latency (~250cy) between tanh chunks (VALUBusy stuck at 35%).
// Arithmetic order IDENTICAL -> outputs bit-identical.
__global__ __launch_bounds__(256, 4) void pair_kernel(
                            const float* __restrict__ dl,
                            const float* __restrict__ dr,
                            const float* __restrict__ U,
                            const float* __restrict__ bias,
                            float* __restrict__ out,
                            double* __restrict__ ws_acc) {
  int blk = blockIdx.x;          // b*64 + iq*2 + jseg
  int b = blk >> 6;              // 0..15
  int i0 = ((blk >> 1) & 31) * 4;
  int j0 = (blk & 1) * 64;
  int t = threadIdx.x;
  int dp = t & 15;
  int jj = t >> 4;

  __shared__ float dlS[4][Dn];        // 4 KB, cooperative coalesced stage
  __shared__ float pS[4][64 * 17];    // [row][jl*17 + dp], padded, 17 KB
  __shared__ float redS[8];

  // stage dl rows i0..i0+3 with one coalesced float4 load per thread
  ((float4*)dlS)[t] = ((const float4*)(dl + (size_t)(b * Ln + i0) * Dn))[t];

  float Ur[16];
  {
    const float4* U4 = (const float4*)(U + dp * 16);
#pragma unroll
    for (int q = 0; q < 4; ++q) {
      float4 u = U4[q];
      Ur[4*q+0] = u.x; Ur[4*q+1] = u.y; Ur[4*q+2] = u.z; Ur[4*q+3] = u.w;
    }
  }
  __syncthreads();

  float dlr[4][16];
#pragma unroll
  for (int r = 0; r < 4; ++r) {
#pragma unroll
    for (int q = 0; q < 4; ++q) {
      float4 a = *(const float4*)&dlS[r][dp * 16 + q * 4];
      dlr[r][4*q+0] = a.x; dlr[r][4*q+1] = a.y; dlr[r][4*q+2] = a.z; dlr[r][4*q+3] = a.w;
    }
  }

  const float* drt = dr + (size_t)b * Ln * Dn + (size_t)(j0 + jj) * Dn + dp * 16;
  float4 vbuf[2][4];               // static after full unroll (no scratch)
  {
    const float4* drp = (const float4*)drt;
#pragma unroll
    for (int q = 0; q < 4; ++q) vbuf[0][q] = drp[q];
  }
#pragma unroll
  for (int tl = 0; tl < 4; ++tl) {
    if (tl < 3) {                  // prefetch next tl during this tl's tanh
      const float4* drn = (const float4*)(drt + (size_t)(tl + 1) * 16 * Dn);
#pragma unroll
      for (int q = 0; q < 4; ++q) vbuf[(tl + 1) & 1][q] = drn[q];
    }
    float a0 = 0.f, a1 = 0.f, a2 = 0.f, a3 = 0.f;
#pragma unroll
    for (int q = 0; q < 4; ++q) {
      float4 v = vbuf[tl & 1][q];
#pragma unroll
      for (int c = 0; c < 4; ++c) {
        float dv = (c == 0) ? v.x : (c == 1) ? v.y : (c == 2) ? v.z : v.w;
        float uv = Ur[4*q+c];
        a0 = fmaf(fast_tanh(dlr[0][4*q+c] + dv), uv, a0);
        a1 = fmaf(fast_tanh(dlr[1][4*q+c] + dv), uv, a1);
        a2 = fmaf(fast_tanh(dlr[2][4*q+c] + dv), uv, a2);
        a3 = fmaf(fast_tanh(dlr[3][4*q+c] + dv), uv, a3);
      }
    }
    int sa = (tl * 16 + jj) * 17 + dp;   // jl*17 + dp, jl = tl*16+jj
    pS[0][sa] = a0; pS[1][sa] = a1; pS[2][sa] = a2; pS[3][sa] = a3;
  }
  __syncthreads();

  // epilogue: 256 outputs (4 rows x 64 j); thread t -> row = t>>6, jl = t&63
  int row = t >> 6;
  int jl = t & 63;
  int j = j0 + jl;
  const float* ps = &pS[row][jl * 17];
  float tot = 0.0f;
#pragma unroll
  for (int k = 0; k < 16; ++k) tot += ps[k];   // dp-ascending, same as R9
  int i = i0 + row;
  float l = tot + bias[0] - ((j == i) ? 1.0e8f : 0.0f);
  float e = __expf(-l);                       // l=-1e8 -> inf
  float p = __builtin_amdgcn_rcpf(1.0f + e);  // -> 0 on diagonal
  unsigned n = ((unsigned)(b * Ln + i) << 7) | (unsigned)j;
  unsigned bits = threefry_bits(0u, n);
  float u = __uint_as_float((bits >> 9) | 0x3f800000u) - 1.0f;
  float smp = (u < p) ? 1.0f : 0.0f;
  float sp_pos = softplus_f(l);
  float sp_neg = softplus_f(-l);
  float ent = p * sp_neg + (1.0f - p) * sp_pos;
  size_t idx = (size_t)(b * Ln + i) * Ln + j;
  out[OFF_MASK + idx] = l;
  out[OFF_SMP + idx] = smp;
  out[OFF_ENT + idx] = ent;
  atomicAdd(&out[OFF_GRAPH + i * Ln + j], smp * 0.0625f);
  float ent_v = ent;
  float lse_v = sp_pos - l * smp;

  // reduce over the 4 waves (all lanes valid)
#pragma unroll
  for (int off = 32; off > 0; off >>= 1) {
    ent_v += __shfl_down(ent_v, off);
    lse_v += __shfl_down(lse_v, off);
  }
  if ((t & 63) == 0) {
    redS[(t >> 6) * 2 + 0] = ent_v;
    redS[(t >> 6) * 2 + 1] = lse_v;
  }
  __syncthreads();
  if (t == 0) {
    float es = redS[0] + redS[2] + redS[4] + redS[6];
    float ls = redS[1] + redS[3] + redS[5] + redS[7];
    atomicAdd(&ws_acc[b], (double)es);
    atomicAdd(&ws_acc[16], (double)ls);
    __threadfence();   // make this block's ws atomics visible before counter
    unsigned int* ctr = (unsigned int*)&ws_acc[17];
    unsigned done = atomicAdd(ctr, 1u);
    if (done == (unsigned)(gridDim.x - 1)) {
      // fused finalize: all blocks' device-scope atomics are complete.
      // atomicAdd(,0.0) = L2-coherent read (bypasses potentially stale L1).
      double ls_tot = atomicAdd(&ws_acc[16], 0.0);
      out[OFF_LSE] = (float)(ls_tot / (double)(Bn * Ln * Ln));
      for (int q = 0; q < Bn; ++q) {
        double ev = atomicAdd(&ws_acc[q], 0.0);
        out[OFF_EREG + q] = (float)(ev / (double)(Ln * Ln));
      }
    }
  }
}

extern "C" void kernel_launch(void* const* d_in, const int* in_sizes, int n_in,
                              void* d_out, int out_size, void* d_ws, size_t ws_size,
                              hipStream_t stream) {
  const float* enc = (const float*)d_in[0];
  const float* Wl = (const float*)d_in[1];
  const float* Wr = (const float*)d_in[2];
  const float* U = (const float*)d_in[3];
  const float* bias = (const float*)d_in[4];
  float* out = (float*)d_out;

  // ws layout: dl (2048*256 f32), dr (2048*256 f32), 17 dbl acc + counter
  float* dl = (float*)d_ws;
  float* dr = dl + (size_t)Bn * Ln * Dn;
  double* ws_acc = (double*)(dr + (size_t)Bn * Ln * Dn);

  proj_kernel<<<512, 256, 0, stream>>>(enc, Wl, Wr, dl, dr, out, ws_acc);
  pair_kernel<<<Bn * Ln / 2, 256, 0, stream>>>(dl, dr, U, bias, out, ws_acc);
}